// Round 8
// baseline (295.294 us; speedup 1.0000x reference)
//
#include <hip/hip_runtime.h>
#include <cfloat>
#include <cmath>

#define NB 2048
#define BB 16
#define DD 128
#define HH 64
#define MAXC 5
#define BPB 8      // blocks per batch
#define SLICE 256  // nodes per block
#define MT 512     // threads per main block

// ---- ws float offsets ----
#define OFF_P 0                              // [BB*NB][HH] 8 MB
#define OFF_PART (OFF_P + BB * NB * HH)      // [BB][16][DD]
#define OFF_SYNC (OFF_PART + BB * 16 * DD)   // u32 cnt[BB]
#define OFF_K0 (OFF_SYNC + 16)               // u64 [BB][MAXC]
#define OFF_K1 (OFF_K0 + BB * MAXC * 2)      // u64 [BB][MAXC]
#define OFF_K2 (OFF_K1 + BB * MAXC * 2)      // u64 [BB][MAXC][BPB][2]

// ---------------- Threefry-2x32 (JAX-exact) ----------------
__device__ __forceinline__ unsigned rotl32(unsigned v, int d) {
  return (v << d) | (v >> (32 - d));
}

__device__ __forceinline__ void tf2x32(unsigned k0, unsigned k1, unsigned x0, unsigned x1,
                                       unsigned& o0, unsigned& o1) {
  unsigned ks2 = k0 ^ k1 ^ 0x1BD11BDAu;
  x0 += k0; x1 += k1;
#define RND(r) { x0 += x1; x1 = rotl32(x1, r); x1 ^= x0; }
  RND(13) RND(15) RND(26) RND(6)   x0 += k1;  x1 += ks2 + 1u;
  RND(17) RND(29) RND(16) RND(24)  x0 += ks2; x1 += k0 + 2u;
  RND(13) RND(15) RND(26) RND(6)   x0 += k0;  x1 += k1 + 3u;
  RND(17) RND(29) RND(16) RND(24)  x0 += k1;  x1 += ks2 + 4u;
  RND(13) RND(15) RND(26) RND(6)   x0 += ks2; x1 += k0 + 5u;
#undef RND
  o0 = x0; o1 = x1;
}

__device__ __forceinline__ float gumbel_for(unsigned k0, unsigned k1, unsigned idx) {
  unsigned o0, o1;
  tf2x32(k0, k1, 0u, idx, o0, o1);
  unsigned bits = o0 ^ o1;
  float u = __uint_as_float((bits >> 9) | 0x3f800000u) - 1.0f;
  float uu = u + 1e-8f;
  return -logf(-logf(uu) + 1e-8f);
}

__device__ __forceinline__ unsigned long long packKey(float y, int n) {
  unsigned u = __float_as_uint(y);
  u = (u & 0x80000000u) ? ~u : (u | 0x80000000u);
  return ((unsigned long long)u << 32) | (unsigned)(~(unsigned)n);
}
__device__ __forceinline__ int decodeKey(unsigned long long k) {
  return k ? (int)(~(unsigned)k) : -1;
}

// ---------------- prep: P-GEMM + mean partials + sync/key zeroing ----------------
__global__ __launch_bounds__(1024) void gvp_prep(
    const float* __restrict__ x, const float* __restrict__ W1, float* __restrict__ ws) {
  __shared__ __align__(16) float s_W1[HH][DD + 4];
  __shared__ float sp[8][DD];
  const int bid = blockIdx.x, tid = threadIdx.x;
  float* P = ws + OFF_P;
  float* partial = ws + OFF_PART;

  if (bid < 128) {
    for (int i = tid; i < HH * (DD / 4); i += 1024) {
      int r = i >> 5, q = i & 31;
      *(float4*)&s_W1[r][q * 4] = *(const float4*)(W1 + (size_t)r * (DD + HH) + q * 4);
    }
    __syncthreads();
    const int jg = tid & 15, ng = tid >> 4;
    const int j0 = jg * 4;
    const size_t n0 = (size_t)bid * 256 + ng * 4;
    const float4* x4 = (const float4*)x;
    float acc[4][4];
#pragma unroll
    for (int i = 0; i < 4; i++)
#pragma unroll
      for (int q = 0; q < 4; q++) acc[i][q] = 0.f;
    for (int kq = 0; kq < 32; kq++) {
      float4 xv[4], wv[4];
#pragma unroll
      for (int i = 0; i < 4; i++) xv[i] = x4[(n0 + i) * 32 + kq];
#pragma unroll
      for (int q = 0; q < 4; q++) wv[q] = *(const float4*)&s_W1[j0 + q][kq * 4];
#pragma unroll
      for (int i = 0; i < 4; i++)
#pragma unroll
        for (int q = 0; q < 4; q++)
          acc[i][q] += xv[i].x * wv[q].x + xv[i].y * wv[q].y +
                       xv[i].z * wv[q].z + xv[i].w * wv[q].w;
    }
#pragma unroll
    for (int i = 0; i < 4; i++)
#pragma unroll
      for (int q = 0; q < 4; q++)
        P[(n0 + i) * HH + j0 + q] = acc[i][q];
  } else if (bid < 384) {
    const int bm = bid - 128;
    const int b = bm >> 4, chunk = bm & 15;
    const int d = tid & (DD - 1), part = tid >> 7;
    float acc = 0.f;
    const int base = chunk * 128 + part;
#pragma unroll
    for (int k = 0; k < 16; k++)
      acc += x[((size_t)b * NB + base + k * 8) * DD + d];
    sp[part][d] = acc;
    __syncthreads();
    if (tid < DD) {
      float m = 0.f;
#pragma unroll
      for (int p = 0; p < 8; p++) m += sp[p][tid];
      partial[((size_t)b * 16 + chunk) * DD + tid] = m;
    }
  } else {
    // zero barrier counters + K0/K1 argmax slots (K2 is written-before-read)
    int nz = 16 + BB * MAXC * 2 + BB * MAXC * 2;  // 336 floats
    if (tid < nz) ws[OFF_SYNC + tid] = 0.f;
  }
}

// ---------------- main: 8 blocks x 512 thr per batch, device barriers ----------------
__global__ __launch_bounds__(MT) void gvp_main(
    const float* __restrict__ x, const float* __restrict__ adj, const int* __restrict__ mask,
    const float* __restrict__ W1, const float* __restrict__ b1,
    const float* __restrict__ W2, const float* __restrict__ b2,
    const float* __restrict__ Wc, const float* __restrict__ bc,
    const float* __restrict__ Wih, const float* __restrict__ Whh,
    const float* __restrict__ bih, const float* __restrict__ bhh,
    float* __restrict__ ws,
    float* __restrict__ out_feat, float* __restrict__ out_adjm, float* __restrict__ out_assign) {
  const int gb = blockIdx.x;
  const int b = gb >> 3, blk = gb & 7;
  const int base = blk * SLICE;
  const int tid = threadIdx.x;

  __shared__ __align__(16) float s_P[SLICE][HH + 4];        // 69.6 KB (node-major, padded)
  __shared__ __align__(16) float s_Whh[3 * HH][HH + 4];     // 52.2 KB
  __shared__ __align__(16) float s_W1c[HH][HH + 4];         // 17.4 KB
  __shared__ __align__(16) float s_logits[SLICE];
  __shared__ unsigned char s_avail[SLICE], s_reach[SLICE], s_assignB[SLICE];
  __shared__ short s_flist[128];
  __shared__ int s_cnt;
  __shared__ __align__(16) float s_hist[MAXC][DD];
  __shared__ __align__(16) float s_giAll[MAXC][3 * HH];
  __shared__ __align__(16) float s_h[2][HH];
  __shared__ __align__(16) float s_mean[DD], s_ctx[HH], s_q[HH];
  __shared__ float sp[4][DD];
  __shared__ float s_bih[3 * HH], s_bhh[3 * HH], s_b1[HH], s_W2[HH];
  __shared__ float s_b2v;
  __shared__ unsigned long long s_redk[8], s_t2r[8][2], s_mrg[17], s_m0;

  unsigned* cnt = (unsigned*)(ws + OFF_SYNC) + b;
  unsigned long long* K0 = (unsigned long long*)(ws + OFF_K0) + b * MAXC;
  unsigned long long* K1 = (unsigned long long*)(ws + OFF_K1) + b * MAXC;
  unsigned long long* K2 = (unsigned long long*)(ws + OFF_K2);
  const size_t xb = (size_t)b * NB * DD;
  int bar = 0;
  int hp = 0;

  auto barrier = [&]() {
    __threadfence();
    __syncthreads();
    ++bar;
    if (tid == 0) {
      __hip_atomic_fetch_add(cnt, 1u, __ATOMIC_RELEASE, __HIP_MEMORY_SCOPE_AGENT);
      while (__hip_atomic_load(cnt, __ATOMIC_ACQUIRE, __HIP_MEMORY_SCOPE_AGENT) <
             (unsigned)(BPB * bar))
        __builtin_amdgcn_s_sleep(1);
    }
    __syncthreads();
  };

  // q = b1 + W1[:,DD:] @ h  (256 threads)
  auto qFromCtx = [&]() {
    if (tid < 4 * HH) {
      int row = tid >> 2, g = tid & 3;
      const float4* wr = (const float4*)&s_W1c[row][0] + g * 4;
      const float4* c4 = (const float4*)s_h[hp] + g * 4;
      float s = 0.f;
#pragma unroll
      for (int i = 0; i < 4; i++) {
        float4 w = wr[i], cc = c4[i];
        s += w.x * cc.x + w.y * cc.y + w.z * cc.z + w.w * cc.w;
      }
      s += __shfl_xor(s, 1);
      s += __shfl_xor(s, 2);
      if (g == 0) s_q[row] = s + s_b1[row];
    }
  };

  auto gruStep = [&](int t) {
    if (tid < 4 * HH) {
      int row = tid >> 2, g = tid & 3;
      const float4* h4 = (const float4*)s_h[hp] + g * 4;
      float4 hv[4];
#pragma unroll
      for (int i = 0; i < 4; i++) hv[i] = h4[i];
      const float4* wr = (const float4*)&s_Whh[row][0] + g * 4;
      const float4* wz = (const float4*)&s_Whh[HH + row][0] + g * 4;
      const float4* wn = (const float4*)&s_Whh[2 * HH + row][0] + g * 4;
      float sr = 0.f, sz = 0.f, sn = 0.f;
#pragma unroll
      for (int i = 0; i < 4; i++) {
        float4 a = wr[i], bz = wz[i], cn = wn[i], h = hv[i];
        sr += a.x * h.x + a.y * h.y + a.z * h.z + a.w * h.w;
        sz += bz.x * h.x + bz.y * h.y + bz.z * h.z + bz.w * h.w;
        sn += cn.x * h.x + cn.y * h.y + cn.z * h.z + cn.w * h.w;
      }
      sr += __shfl_xor(sr, 1); sr += __shfl_xor(sr, 2);
      sz += __shfl_xor(sz, 1); sz += __shfl_xor(sz, 2);
      sn += __shfl_xor(sn, 1); sn += __shfl_xor(sn, 2);
      if (g == 0) {
        float r = 1.f / (1.f + expf(-(s_giAll[t][row] + sr + s_bhh[row])));
        float z = 1.f / (1.f + expf(-(s_giAll[t][HH + row] + sz + s_bhh[HH + row])));
        float nn = tanhf(s_giAll[t][2 * HH + row] + r * (sn + s_bhh[2 * HH + row]));
        s_h[hp ^ 1][row] = (1.f - z) * nn + z * s_h[hp][row];
      }
    }
  };

  // logits for this block's slice (P in LDS) + sel0 scan/post for cluster cc
  auto logitsSel0 = [&](int cc) {
    unsigned ka, kb;
    tf2x32(0u, 42u, 0u, (unsigned)(2 * cc), ka, kb);
    int node = tid >> 1, sub = tid & 1;
    const float4* pr = (const float4*)&s_P[node][0] + sub * 8;
    const float4* q4 = (const float4*)s_q + sub * 8;
    const float4* w4 = (const float4*)s_W2 + sub * 8;
    float l = 0.f;
#pragma unroll
    for (int i = 0; i < 8; i++) {
      float4 p = pr[i], qv = q4[i], w = w4[i];
      l += w.x * fmaxf(p.x + qv.x, 0.f) + w.y * fmaxf(p.y + qv.y, 0.f) +
           w.z * fmaxf(p.z + qv.z, 0.f) + w.w * fmaxf(p.w + qv.w, 0.f);
    }
    l += __shfl_xor(l, 1);
    l += s_b2v;
    unsigned long long key = 0ull;
    if (sub == 0) {
      s_logits[node] = l;
      if (s_avail[node]) {
        float y = l + gumbel_for(ka, kb, (unsigned)(b * NB + base + node));
        key = packKey(y, base + node);
      }
    }
#pragma unroll
    for (int off = 32; off; off >>= 1) {
      unsigned long long o = __shfl_down(key, off);
      key = o > key ? o : key;
    }
    if ((tid & 63) == 0) s_redk[tid >> 6] = key;
    __syncthreads();
    if (tid == 0) {
      unsigned long long m = s_redk[0];
#pragma unroll
      for (int i = 1; i < 8; i++) m = s_redk[i] > m ? s_redk[i] : m;
      if (m) atomicMax(&K0[cc], m);
    }
  };

  // ======== one-time staging ========
  {
    const float4* P4 = (const float4*)(ws + OFF_P);
    for (int i = tid; i < SLICE * 16; i += MT) {
      int node = i >> 4, q = i & 15;
      *(float4*)&s_P[node][q * 4] = P4[(size_t)(b * NB + base + node) * 16 + q];
    }
  }
  for (int i = tid; i < 3 * HH * 16; i += MT) {
    int r = i >> 4, q = i & 15;
    *(float4*)&s_Whh[r][q * 4] = *(const float4*)(Whh + (size_t)r * HH + q * 4);
  }
  for (int i = tid; i < HH * 16; i += MT) {
    int r = i >> 4, q = i & 15;
    *(float4*)&s_W1c[r][q * 4] = *(const float4*)(W1 + (size_t)r * (DD + HH) + DD + q * 4);
  }
  if (tid < 3 * HH) { s_bih[tid] = bih[tid]; s_bhh[tid] = bhh[tid]; }
  if (tid < HH) { s_b1[tid] = b1[tid]; s_W2[tid] = W2[tid]; s_h[0][tid] = 0.f; }
  if (tid < SLICE) {
    s_avail[tid] = (mask[b * NB + base + tid] != 0) ? 1 : 0;
    s_assignB[tid] = 0;
  }
  if (tid == 0) s_b2v = b2[0];
  {
    int d = tid & (DD - 1), p = tid >> 7;
    float a = 0.f;
    for (int k = p; k < 16; k += 4) a += ws[OFF_PART + ((size_t)b * 16 + k) * DD + d];
    sp[p][d] = a;
  }
  __syncthreads();
  if (tid < DD)
    s_mean[tid] = (sp[0][tid] + sp[1][tid] + sp[2][tid] + sp[3][tid]) * (1.0f / NB);
  __syncthreads();
  if (tid < 4 * HH) {  // ctx = bc + Wc @ mean (replicated)
    int row = tid >> 2, g = tid & 3;
    const float4* wr = (const float4*)(Wc + (size_t)row * DD) + g * 8;
    const float4* m4 = (const float4*)s_mean + g * 8;
    float s = 0.f;
#pragma unroll
    for (int i = 0; i < 8; i++) {
      float4 w = wr[i], m = m4[i];
      s += w.x * m.x + w.y * m.y + w.z * m.z + w.w * m.w;
    }
    s += __shfl_xor(s, 1);
    s += __shfl_xor(s, 2);
    if (g == 0) { s_ctx[row] = s + bc[row]; s_h[0][row] = 0.f; }
  }
  __syncthreads();
  // q0 = b1 + W1c @ ctx  (use s_ctx, not h)
  if (tid < 4 * HH) {
    int row = tid >> 2, g = tid & 3;
    const float4* wr = (const float4*)&s_W1c[row][0] + g * 4;
    const float4* c4 = (const float4*)s_ctx + g * 4;
    float s = 0.f;
#pragma unroll
    for (int i = 0; i < 4; i++) {
      float4 w = wr[i], cc = c4[i];
      s += w.x * cc.x + w.y * cc.y + w.z * cc.z + w.w * cc.w;
    }
    s += __shfl_xor(s, 1);
    s += __shfl_xor(s, 2);
    if (g == 0) s_q[row] = s + s_b1[row];
  }
  __syncthreads();
  logitsSel0(0);
  barrier();  // #1

  for (int c = 0; c < MAXC; c++) {
    // ======== phase2: seed merge -> BFS -> sel1 + sel2-top2 post ========
    if (tid == 0) {
      s_cnt = 0;
      s_m0 = __hip_atomic_load(&K0[c], __ATOMIC_ACQUIRE, __HIP_MEMORY_SCOPE_AGENT);
    }
    if (tid < SLICE) s_reach[tid] = 0;
    __syncthreads();
    const int seed = decodeKey(s_m0);
    if (tid == 0 && seed >= base && seed < base + SLICE) s_avail[seed - base] = 0;
    if (seed >= 0) {
      float4 a = *(const float4*)(adj + ((size_t)b * NB + seed) * NB + tid * 4);
      int col = tid * 4;
#pragma unroll
      for (int e = 0; e < 4; e++) {
        float v = (e == 0) ? a.x : (e == 1) ? a.y : (e == 2) ? a.z : a.w;
        if (v > 0.f) {
          int cg = col + e;
          if (cg >= base && cg < base + SLICE) s_reach[cg - base] = 1;
          int p = atomicAdd(&s_cnt, 1);
          if (p < 128) s_flist[p] = (short)cg;
        }
      }
      if (tid == 0 && seed >= base && seed < base + SLICE) s_reach[seed - base] = 1;
    }
    __syncthreads();
    if (seed >= 0) {  // hop1: my 256-col slice of each frontier row
      int fc = min(s_cnt, 128);
      int lane = tid & 63;
      for (int fi = tid >> 6; fi < fc; fi += 8) {
        int r = s_flist[fi];
        float4 a = *(const float4*)(adj + ((size_t)b * NB + r) * NB + base + lane * 4);
        if (a.x > 0.f) s_reach[lane * 4] = 1;
        if (a.y > 0.f) s_reach[lane * 4 + 1] = 1;
        if (a.z > 0.f) s_reach[lane * 4 + 2] = 1;
        if (a.w > 0.f) s_reach[lane * 4 + 3] = 1;
      }
    }
    __syncthreads();
    {  // sel1 argmax + sel2 top-2 over my slice
      unsigned k1a, k1b, k2a, k2b;
      tf2x32(0u, 42u, 0u, (unsigned)(2 * c + 1000), k1a, k1b);
      tf2x32(0u, 42u, 0u, (unsigned)(2 * c + 1001), k2a, k2b);
      unsigned long long key1 = 0ull, t1 = 0ull, t2 = 0ull;
      if (tid < SLICE && s_avail[tid] && s_reach[tid]) {
        unsigned gidx = (unsigned)(b * NB + base + tid);
        float lg = s_logits[tid];
        key1 = packKey(lg + gumbel_for(k1a, k1b, gidx), base + tid);
        t1 = packKey(lg + gumbel_for(k2a, k2b, gidx), base + tid);
      }
#pragma unroll
      for (int off = 32; off; off >>= 1) {
        unsigned long long o = __shfl_down(key1, off);
        key1 = o > key1 ? o : key1;
        unsigned long long o1 = __shfl_down(t1, off);
        unsigned long long o2 = __shfl_down(t2, off);
        unsigned long long lo = t1 < o1 ? t1 : o1;
        unsigned long long hi2 = t2 > o2 ? t2 : o2;
        t1 = t1 > o1 ? t1 : o1;
        t2 = lo > hi2 ? lo : hi2;
      }
      if ((tid & 63) == 0) {
        int w = tid >> 6;
        s_redk[w] = key1;
        s_t2r[w][0] = t1;
        s_t2r[w][1] = t2;
      }
      __syncthreads();
      if (tid == 0) {
        unsigned long long m = 0ull, u1 = 0ull, u2 = 0ull;
#pragma unroll
        for (int i = 0; i < 8; i++) {
          if (s_redk[i] > m) m = s_redk[i];
          unsigned long long k = s_t2r[i][0];
          if (k > u1) { u2 = u1; u1 = k; } else if (k > u2) u2 = k;
          k = s_t2r[i][1];
          if (k > u1) { u2 = u1; u1 = k; } else if (k > u2) u2 = k;
        }
        if (m) atomicMax(&K1[c], m);
        unsigned long long* slot = K2 + ((size_t)(b * MAXC + c) * BPB + blk) * 2;
        slot[0] = u1;
        slot[1] = u2;
      }
    }
    barrier();  // end of phase2

    // ======== phase3: winner merge -> emb -> gi -> GRU -> q -> next sel0 ========
    if (tid < 17) {
      unsigned long long v =
          (tid == 0)
              ? __hip_atomic_load(&K1[c], __ATOMIC_ACQUIRE, __HIP_MEMORY_SCOPE_AGENT)
              : __hip_atomic_load(K2 + (size_t)(b * MAXC + c) * BPB * 2 + tid - 1,
                                  __ATOMIC_ACQUIRE, __HIP_MEMORY_SCOPE_AGENT);
      s_mrg[tid] = v;
    }
    __syncthreads();
    const int w1 = decodeKey(s_mrg[0]);
    int w2;
    {
      unsigned long long t1 = 0ull, t2 = 0ull;
#pragma unroll
      for (int i = 1; i < 17; i++) {
        unsigned long long k = s_mrg[i];
        if (k > t1) { t2 = t1; t1 = k; } else if (k > t2) t2 = k;
      }
      int i1 = decodeKey(t1);
      w2 = (i1 == w1) ? decodeKey(t2) : i1;
    }
    if (tid == 0) {
      if (w1 >= base && w1 < base + SLICE) s_avail[w1 - base] = 0;
      if (w2 >= base && w2 < base + SLICE) s_avail[w2 - base] = 0;
      if (seed >= base && seed < base + SLICE) s_assignB[seed - base] |= (unsigned char)(1 << c);
      if (w1 >= base && w1 < base + SLICE) s_assignB[w1 - base] |= (unsigned char)(1 << c);
      if (w2 >= base && w2 < base + SLICE) s_assignB[w2 - base] |= (unsigned char)(1 << c);
    }
    {
      int mc = (seed >= 0) + (w1 >= 0) + (w2 >= 0);
      float invmc = 1.0f / fmaxf((float)mc, 1.0f);
      if (tid < DD) {
        float acc = 0.f;
        if (seed >= 0) acc += x[xb + (size_t)seed * DD + tid];
        if (w1 >= 0) acc += x[xb + (size_t)w1 * DD + tid];
        if (w2 >= 0) acc += x[xb + (size_t)w2 * DD + tid];
        float e = acc * invmc;
        s_hist[c][tid] = e;
        if (blk == 0) out_feat[((size_t)b * MAXC + c) * DD + tid] = e;
      }
    }
    __syncthreads();

    if (c + 1 < MAXC) {
      if (tid < 2 * 3 * HH) {  // gi[c] = bih + Wih @ emb (replicated)
        int row = tid >> 1, half = tid & 1;
        const float4* wr = (const float4*)(Wih + (size_t)row * DD) + half * 16;
        const float4* h4 = (const float4*)s_hist[c] + half * 16;
        float s = 0.f;
#pragma unroll
        for (int i = 0; i < 16; i++) {
          float4 w = wr[i], h = h4[i];
          s += w.x * h.x + w.y * h.y + w.z * h.z + w.w * h.w;
        }
        s += __shfl_xor(s, 1);
        if (half == 0) s_giAll[c][row] = s + s_bih[row];
      }
      __syncthreads();
      for (int t = 0; t <= c; t++) {
        gruStep(t);
        hp ^= 1;
        __syncthreads();
      }
      qFromCtx();
      __syncthreads();
      logitsSel0(c + 1);
      barrier();  // end of phase3
    } else {
      // final writes (assign bits complete after this cluster's update above)
      for (int r = tid; r < SLICE * MAXC; r += MT) {
        int i = r / MAXC, cc = r - MAXC * i;
        out_assign[((size_t)(b * NB + base + i)) * MAXC + cc] =
            (float)((s_assignB[i] >> cc) & 1u);
      }
      if (gb == 0) {
        for (int i = tid; i < BB * MAXC * MAXC; i += MT) {
          int j = i % (MAXC * MAXC);
          out_adjm[i] = ((j / MAXC) == (j % MAXC)) ? 0.f : 1.f;
        }
      }
    }
  }
}

extern "C" void kernel_launch(void* const* d_in, const int* in_sizes, int n_in,
                              void* d_out, int out_size, void* d_ws, size_t ws_size,
                              hipStream_t stream) {
  const float* x   = (const float*)d_in[0];
  const float* adj = (const float*)d_in[1];
  const int*   mask= (const int*)d_in[2];
  const float* W1  = (const float*)d_in[3];
  const float* b1  = (const float*)d_in[4];
  const float* W2  = (const float*)d_in[5];
  const float* b2  = (const float*)d_in[6];
  const float* Wc  = (const float*)d_in[7];
  const float* bc  = (const float*)d_in[8];
  const float* Wih = (const float*)d_in[9];
  const float* Whh = (const float*)d_in[10];
  const float* bih = (const float*)d_in[11];
  const float* bhh = (const float*)d_in[12];

  float* ws = (float*)d_ws;
  float* out = (float*)d_out;
  float* out_feat = out;                                     // [B,5,D]
  float* out_adjm = out + (size_t)BB * MAXC * DD;            // [B,5,5]
  float* out_assign = out_adjm + (size_t)BB * MAXC * MAXC;   // [B,N,5]

  hipLaunchKernelGGL(gvp_prep, dim3(385), dim3(1024), 0, stream, x, W1, ws);
  hipLaunchKernelGGL(gvp_main, dim3(BB * BPB), dim3(MT), 0, stream,
                     x, adj, mask, W1, b1, W2, b2, Wc, bc, Wih, Whh, bih, bhh, ws,
                     out_feat, out_adjm, out_assign);
}

// Round 9
// 251.794 us; speedup vs baseline: 1.1728x; 1.1728x over previous
//
#include <hip/hip_runtime.h>
#include <cfloat>
#include <cmath>

#define NB 2048
#define BB 16
#define DD 128
#define HH 64
#define MAXC 5
#define BPB 8      // blocks per batch
#define SLICE 256  // nodes per block
#define MT 512     // threads per main block

// ---- ws float offsets ----
#define OFF_P 0                              // [BB*NB][HH] 8 MB
#define OFF_PART (OFF_P + BB * NB * HH)      // [BB][16][DD]
#define OFF_SYNCBASE (OFF_PART + BB * 16 * DD)
#define SYNC_STRIDE 512                      // floats (2 KB) per batch, padded
// per-batch layout (float offsets within the 512-float block):
//   +0   cnt (u32)                  [own 128-B line]
//   +32  K0[MAXC] (u64)             [own line]
//   +64  K1[MAXC] (u64)
//   +96  K2[MAXC][BPB][2] (u64)     160 floats

// ---------------- Threefry-2x32 (JAX-exact) ----------------
__device__ __forceinline__ unsigned rotl32(unsigned v, int d) {
  return (v << d) | (v >> (32 - d));
}

__device__ __forceinline__ void tf2x32(unsigned k0, unsigned k1, unsigned x0, unsigned x1,
                                       unsigned& o0, unsigned& o1) {
  unsigned ks2 = k0 ^ k1 ^ 0x1BD11BDAu;
  x0 += k0; x1 += k1;
#define RND(r) { x0 += x1; x1 = rotl32(x1, r); x1 ^= x0; }
  RND(13) RND(15) RND(26) RND(6)   x0 += k1;  x1 += ks2 + 1u;
  RND(17) RND(29) RND(16) RND(24)  x0 += ks2; x1 += k0 + 2u;
  RND(13) RND(15) RND(26) RND(6)   x0 += k0;  x1 += k1 + 3u;
  RND(17) RND(29) RND(16) RND(24)  x0 += k1;  x1 += ks2 + 4u;
  RND(13) RND(15) RND(26) RND(6)   x0 += ks2; x1 += k0 + 5u;
#undef RND
  o0 = x0; o1 = x1;
}

__device__ __forceinline__ float gumbel_for(unsigned k0, unsigned k1, unsigned idx) {
  unsigned o0, o1;
  tf2x32(k0, k1, 0u, idx, o0, o1);
  unsigned bits = o0 ^ o1;
  float u = __uint_as_float((bits >> 9) | 0x3f800000u) - 1.0f;
  float uu = u + 1e-8f;
  return -logf(-logf(uu) + 1e-8f);
}

__device__ __forceinline__ unsigned long long packKey(float y, int n) {
  unsigned u = __float_as_uint(y);
  u = (u & 0x80000000u) ? ~u : (u | 0x80000000u);
  return ((unsigned long long)u << 32) | (unsigned)(~(unsigned)n);
}
__device__ __forceinline__ int decodeKey(unsigned long long k) {
  return k ? (int)(~(unsigned)k) : -1;
}

// ---------------- prep: P-GEMM + mean partials + sync zeroing ----------------
__global__ __launch_bounds__(1024) void gvp_prep(
    const float* __restrict__ x, const float* __restrict__ W1, float* __restrict__ ws) {
  __shared__ __align__(16) float s_W1[HH][DD + 4];
  __shared__ float sp[8][DD];
  const int bid = blockIdx.x, tid = threadIdx.x;
  float* P = ws + OFF_P;
  float* partial = ws + OFF_PART;

  if (bid < 128) {
    for (int i = tid; i < HH * (DD / 4); i += 1024) {
      int r = i >> 5, q = i & 31;
      *(float4*)&s_W1[r][q * 4] = *(const float4*)(W1 + (size_t)r * (DD + HH) + q * 4);
    }
    __syncthreads();
    const int jg = tid & 15, ng = tid >> 4;
    const int j0 = jg * 4;
    const size_t n0 = (size_t)bid * 256 + ng * 4;
    const float4* x4 = (const float4*)x;
    float acc[4][4];
#pragma unroll
    for (int i = 0; i < 4; i++)
#pragma unroll
      for (int q = 0; q < 4; q++) acc[i][q] = 0.f;
    for (int kq = 0; kq < 32; kq++) {
      float4 xv[4], wv[4];
#pragma unroll
      for (int i = 0; i < 4; i++) xv[i] = x4[(n0 + i) * 32 + kq];
#pragma unroll
      for (int q = 0; q < 4; q++) wv[q] = *(const float4*)&s_W1[j0 + q][kq * 4];
#pragma unroll
      for (int i = 0; i < 4; i++)
#pragma unroll
        for (int q = 0; q < 4; q++)
          acc[i][q] += xv[i].x * wv[q].x + xv[i].y * wv[q].y +
                       xv[i].z * wv[q].z + xv[i].w * wv[q].w;
    }
#pragma unroll
    for (int i = 0; i < 4; i++)
#pragma unroll
      for (int q = 0; q < 4; q++)
        P[(n0 + i) * HH + j0 + q] = acc[i][q];
  } else if (bid < 384) {
    const int bm = bid - 128;
    const int b = bm >> 4, chunk = bm & 15;
    const int d = tid & (DD - 1), part = tid >> 7;
    float acc = 0.f;
    const int base = chunk * 128 + part;
#pragma unroll
    for (int k = 0; k < 16; k++)
      acc += x[((size_t)b * NB + base + k * 8) * DD + d];
    sp[part][d] = acc;
    __syncthreads();
    if (tid < DD) {
      float m = 0.f;
#pragma unroll
      for (int p = 0; p < 8; p++) m += sp[p][tid];
      partial[((size_t)b * 16 + chunk) * DD + tid] = m;
    }
  } else {
    for (int i = tid; i < BB * SYNC_STRIDE; i += 1024) ws[OFF_SYNCBASE + i] = 0.f;
  }
}

// ---------------- main: 8 blocks x 512 thr per batch, padded device barriers ----------------
__global__ __launch_bounds__(MT) void gvp_main(
    const float* __restrict__ x, const float* __restrict__ adj, const int* __restrict__ mask,
    const float* __restrict__ W1, const float* __restrict__ b1,
    const float* __restrict__ W2, const float* __restrict__ b2,
    const float* __restrict__ Wc, const float* __restrict__ bc,
    const float* __restrict__ Wih, const float* __restrict__ Whh,
    const float* __restrict__ bih, const float* __restrict__ bhh,
    float* __restrict__ ws,
    float* __restrict__ out_feat, float* __restrict__ out_adjm, float* __restrict__ out_assign) {
  const int gb = blockIdx.x;
  // XCD-affinity swizzle: blocks {b, b+16, ..., b+112} share XCD (b % 8) under
  // round-robin dispatch -> all 8 blocks of a batch are XCD-local.
  const int b = gb & 15, blk = gb >> 4;
  const int base = blk * SLICE;
  const int tid = threadIdx.x;

  __shared__ __align__(16) float s_P[SLICE][HH + 4];        // 69.6 KB
  __shared__ __align__(16) float s_Whh[3 * HH][HH + 4];     // 52.2 KB
  __shared__ __align__(16) float s_W1c[HH][HH + 4];         // 17.4 KB
  __shared__ __align__(16) float s_logits[SLICE];
  __shared__ unsigned char s_avail[SLICE], s_reach[SLICE], s_assignB[SLICE];
  __shared__ short s_flist[128];
  __shared__ int s_cnt;
  __shared__ __align__(16) float s_hist[MAXC][DD];
  __shared__ __align__(16) float s_giAll[MAXC][3 * HH];
  __shared__ __align__(16) float s_h[2][HH];
  __shared__ __align__(16) float s_mean[DD], s_ctx[HH], s_q[HH];
  __shared__ float sp[4][DD];
  __shared__ float s_bih[3 * HH], s_bhh[3 * HH], s_b1[HH], s_W2[HH];
  __shared__ float s_b2v;
  __shared__ unsigned long long s_redk[8], s_t2r[8][2], s_mrg[17], s_m0;

  float* syncb = ws + OFF_SYNCBASE + (size_t)b * SYNC_STRIDE;
  unsigned* cnt = (unsigned*)syncb;
  unsigned long long* K0 = (unsigned long long*)(syncb + 32);
  unsigned long long* K1 = (unsigned long long*)(syncb + 64);
  unsigned long long* K2 = (unsigned long long*)(syncb + 96);  // [MAXC][BPB][2]
  const size_t xb = (size_t)b * NB * DD;
  int bar = 0;
  int hp = 0;

  auto barrier = [&]() {
    __threadfence();
    __syncthreads();
    ++bar;
    if (tid == 0) {
      __hip_atomic_fetch_add(cnt, 1u, __ATOMIC_RELEASE, __HIP_MEMORY_SCOPE_AGENT);
      while (__hip_atomic_load(cnt, __ATOMIC_ACQUIRE, __HIP_MEMORY_SCOPE_AGENT) <
             (unsigned)(BPB * bar))
        __builtin_amdgcn_s_sleep(1);
    }
    __syncthreads();
  };

  auto qFromCtx = [&]() {
    if (tid < 4 * HH) {
      int row = tid >> 2, g = tid & 3;
      const float4* wr = (const float4*)&s_W1c[row][0] + g * 4;
      const float4* c4 = (const float4*)s_h[hp] + g * 4;
      float s = 0.f;
#pragma unroll
      for (int i = 0; i < 4; i++) {
        float4 w = wr[i], cc = c4[i];
        s += w.x * cc.x + w.y * cc.y + w.z * cc.z + w.w * cc.w;
      }
      s += __shfl_xor(s, 1);
      s += __shfl_xor(s, 2);
      if (g == 0) s_q[row] = s + s_b1[row];
    }
  };

  auto gruStep = [&](int t) {
    if (tid < 4 * HH) {
      int row = tid >> 2, g = tid & 3;
      const float4* h4 = (const float4*)s_h[hp] + g * 4;
      float4 hv[4];
#pragma unroll
      for (int i = 0; i < 4; i++) hv[i] = h4[i];
      const float4* wr = (const float4*)&s_Whh[row][0] + g * 4;
      const float4* wz = (const float4*)&s_Whh[HH + row][0] + g * 4;
      const float4* wn = (const float4*)&s_Whh[2 * HH + row][0] + g * 4;
      float sr = 0.f, sz = 0.f, sn = 0.f;
#pragma unroll
      for (int i = 0; i < 4; i++) {
        float4 a = wr[i], bz = wz[i], cn = wn[i], h = hv[i];
        sr += a.x * h.x + a.y * h.y + a.z * h.z + a.w * h.w;
        sz += bz.x * h.x + bz.y * h.y + bz.z * h.z + bz.w * h.w;
        sn += cn.x * h.x + cn.y * h.y + cn.z * h.z + cn.w * h.w;
      }
      sr += __shfl_xor(sr, 1); sr += __shfl_xor(sr, 2);
      sz += __shfl_xor(sz, 1); sz += __shfl_xor(sz, 2);
      sn += __shfl_xor(sn, 1); sn += __shfl_xor(sn, 2);
      if (g == 0) {
        float r = 1.f / (1.f + expf(-(s_giAll[t][row] + sr + s_bhh[row])));
        float z = 1.f / (1.f + expf(-(s_giAll[t][HH + row] + sz + s_bhh[HH + row])));
        float nn = tanhf(s_giAll[t][2 * HH + row] + r * (sn + s_bhh[2 * HH + row]));
        s_h[hp ^ 1][row] = (1.f - z) * nn + z * s_h[hp][row];
      }
    }
  };

  auto logitsSel0 = [&](int cc) {
    unsigned ka, kb;
    tf2x32(0u, 42u, 0u, (unsigned)(2 * cc), ka, kb);
    int node = tid >> 1, sub = tid & 1;
    const float4* pr = (const float4*)&s_P[node][0] + sub * 8;
    const float4* q4 = (const float4*)s_q + sub * 8;
    const float4* w4 = (const float4*)s_W2 + sub * 8;
    float l = 0.f;
#pragma unroll
    for (int i = 0; i < 8; i++) {
      float4 p = pr[i], qv = q4[i], w = w4[i];
      l += w.x * fmaxf(p.x + qv.x, 0.f) + w.y * fmaxf(p.y + qv.y, 0.f) +
           w.z * fmaxf(p.z + qv.z, 0.f) + w.w * fmaxf(p.w + qv.w, 0.f);
    }
    l += __shfl_xor(l, 1);
    l += s_b2v;
    unsigned long long key = 0ull;
    if (sub == 0) {
      s_logits[node] = l;
      if (s_avail[node]) {
        float y = l + gumbel_for(ka, kb, (unsigned)(b * NB + base + node));
        key = packKey(y, base + node);
      }
    }
#pragma unroll
    for (int off = 32; off; off >>= 1) {
      unsigned long long o = __shfl_down(key, off);
      key = o > key ? o : key;
    }
    if ((tid & 63) == 0) s_redk[tid >> 6] = key;
    __syncthreads();
    if (tid == 0) {
      unsigned long long m = s_redk[0];
#pragma unroll
      for (int i = 1; i < 8; i++) m = s_redk[i] > m ? s_redk[i] : m;
      if (m) atomicMax(&K0[cc], m);
    }
  };

  // ======== one-time staging ========
  {
    const float4* P4 = (const float4*)(ws + OFF_P);
    for (int i = tid; i < SLICE * 16; i += MT) {
      int node = i >> 4, q = i & 15;
      *(float4*)&s_P[node][q * 4] = P4[(size_t)(b * NB + base + node) * 16 + q];
    }
  }
  for (int i = tid; i < 3 * HH * 16; i += MT) {
    int r = i >> 4, q = i & 15;
    *(float4*)&s_Whh[r][q * 4] = *(const float4*)(Whh + (size_t)r * HH + q * 4);
  }
  for (int i = tid; i < HH * 16; i += MT) {
    int r = i >> 4, q = i & 15;
    *(float4*)&s_W1c[r][q * 4] = *(const float4*)(W1 + (size_t)r * (DD + HH) + DD + q * 4);
  }
  if (tid < 3 * HH) { s_bih[tid] = bih[tid]; s_bhh[tid] = bhh[tid]; }
  if (tid < HH) { s_b1[tid] = b1[tid]; s_W2[tid] = W2[tid]; s_h[0][tid] = 0.f; }
  if (tid < SLICE) {
    s_avail[tid] = (mask[b * NB + base + tid] != 0) ? 1 : 0;
    s_assignB[tid] = 0;
  }
  if (tid == 0) s_b2v = b2[0];
  {
    int d = tid & (DD - 1), p = tid >> 7;
    float a = 0.f;
    for (int k = p; k < 16; k += 4) a += ws[OFF_PART + ((size_t)b * 16 + k) * DD + d];
    sp[p][d] = a;
  }
  __syncthreads();
  if (tid < DD)
    s_mean[tid] = (sp[0][tid] + sp[1][tid] + sp[2][tid] + sp[3][tid]) * (1.0f / NB);
  __syncthreads();
  if (tid < 4 * HH) {  // ctx = bc + Wc @ mean (replicated)
    int row = tid >> 2, g = tid & 3;
    const float4* wr = (const float4*)(Wc + (size_t)row * DD) + g * 8;
    const float4* m4 = (const float4*)s_mean + g * 8;
    float s = 0.f;
#pragma unroll
    for (int i = 0; i < 8; i++) {
      float4 w = wr[i], m = m4[i];
      s += w.x * m.x + w.y * m.y + w.z * m.z + w.w * m.w;
    }
    s += __shfl_xor(s, 1);
    s += __shfl_xor(s, 2);
    if (g == 0) { s_ctx[row] = s + bc[row]; s_h[0][row] = 0.f; }
  }
  __syncthreads();
  if (tid < 4 * HH) {  // q0 = b1 + W1c @ ctx
    int row = tid >> 2, g = tid & 3;
    const float4* wr = (const float4*)&s_W1c[row][0] + g * 4;
    const float4* c4 = (const float4*)s_ctx + g * 4;
    float s = 0.f;
#pragma unroll
    for (int i = 0; i < 4; i++) {
      float4 w = wr[i], cc = c4[i];
      s += w.x * cc.x + w.y * cc.y + w.z * cc.z + w.w * cc.w;
    }
    s += __shfl_xor(s, 1);
    s += __shfl_xor(s, 2);
    if (g == 0) s_q[row] = s + s_b1[row];
  }
  __syncthreads();
  logitsSel0(0);
  barrier();  // #1

  for (int c = 0; c < MAXC; c++) {
    // ======== phase2: seed merge -> BFS -> sel1 + sel2-top2 post ========
    if (tid == 0) {
      s_cnt = 0;
      s_m0 = __hip_atomic_load(&K0[c], __ATOMIC_RELAXED, __HIP_MEMORY_SCOPE_AGENT);
    }
    if (tid < SLICE) s_reach[tid] = 0;
    __syncthreads();
    const int seed = decodeKey(s_m0);
    if (tid == 0 && seed >= base && seed < base + SLICE) s_avail[seed - base] = 0;
    if (seed >= 0) {
      float4 a = *(const float4*)(adj + ((size_t)b * NB + seed) * NB + tid * 4);
      int col = tid * 4;
#pragma unroll
      for (int e = 0; e < 4; e++) {
        float v = (e == 0) ? a.x : (e == 1) ? a.y : (e == 2) ? a.z : a.w;
        if (v > 0.f) {
          int cg = col + e;
          if (cg >= base && cg < base + SLICE) s_reach[cg - base] = 1;
          int p = atomicAdd(&s_cnt, 1);
          if (p < 128) s_flist[p] = (short)cg;
        }
      }
      if (tid == 0 && seed >= base && seed < base + SLICE) s_reach[seed - base] = 1;
    }
    __syncthreads();
    if (seed >= 0) {  // hop1: my 256-col slice of each frontier row
      int fc = min(s_cnt, 128);
      int lane = tid & 63;
      for (int fi = tid >> 6; fi < fc; fi += 8) {
        int r = s_flist[fi];
        float4 a = *(const float4*)(adj + ((size_t)b * NB + r) * NB + base + lane * 4);
        if (a.x > 0.f) s_reach[lane * 4] = 1;
        if (a.y > 0.f) s_reach[lane * 4 + 1] = 1;
        if (a.z > 0.f) s_reach[lane * 4 + 2] = 1;
        if (a.w > 0.f) s_reach[lane * 4 + 3] = 1;
      }
    }
    __syncthreads();
    {  // sel1 argmax + sel2 top-2 over my slice
      unsigned k1a, k1b, k2a, k2b;
      tf2x32(0u, 42u, 0u, (unsigned)(2 * c + 1000), k1a, k1b);
      tf2x32(0u, 42u, 0u, (unsigned)(2 * c + 1001), k2a, k2b);
      unsigned long long key1 = 0ull, t1 = 0ull, t2 = 0ull;
      if (tid < SLICE && s_avail[tid] && s_reach[tid]) {
        unsigned gidx = (unsigned)(b * NB + base + tid);
        float lg = s_logits[tid];
        key1 = packKey(lg + gumbel_for(k1a, k1b, gidx), base + tid);
        t1 = packKey(lg + gumbel_for(k2a, k2b, gidx), base + tid);
      }
#pragma unroll
      for (int off = 32; off; off >>= 1) {
        unsigned long long o = __shfl_down(key1, off);
        key1 = o > key1 ? o : key1;
        unsigned long long o1 = __shfl_down(t1, off);
        unsigned long long o2 = __shfl_down(t2, off);
        unsigned long long lo = t1 < o1 ? t1 : o1;
        unsigned long long hi2 = t2 > o2 ? t2 : o2;
        t1 = t1 > o1 ? t1 : o1;
        t2 = lo > hi2 ? lo : hi2;
      }
      if ((tid & 63) == 0) {
        int w = tid >> 6;
        s_redk[w] = key1;
        s_t2r[w][0] = t1;
        s_t2r[w][1] = t2;
      }
      __syncthreads();
      if (tid == 0) {
        unsigned long long m = 0ull, u1 = 0ull, u2 = 0ull;
#pragma unroll
        for (int i = 0; i < 8; i++) {
          if (s_redk[i] > m) m = s_redk[i];
          unsigned long long k = s_t2r[i][0];
          if (k > u1) { u2 = u1; u1 = k; } else if (k > u2) u2 = k;
          k = s_t2r[i][1];
          if (k > u1) { u2 = u1; u1 = k; } else if (k > u2) u2 = k;
        }
        if (m) atomicMax(&K1[c], m);
        unsigned long long* slot = K2 + ((size_t)c * BPB + blk) * 2;
        slot[0] = u1;
        slot[1] = u2;
      }
    }
    barrier();  // end of phase2

    // ======== phase3: winner merge -> emb -> gi -> GRU -> q -> next sel0 ========
    if (tid < 17) {
      unsigned long long v =
          (tid == 0)
              ? __hip_atomic_load(&K1[c], __ATOMIC_RELAXED, __HIP_MEMORY_SCOPE_AGENT)
              : __hip_atomic_load(K2 + (size_t)c * BPB * 2 + tid - 1,
                                  __ATOMIC_RELAXED, __HIP_MEMORY_SCOPE_AGENT);
      s_mrg[tid] = v;
    }
    __syncthreads();
    const int w1 = decodeKey(s_mrg[0]);
    int w2;
    {
      unsigned long long t1 = 0ull, t2 = 0ull;
#pragma unroll
      for (int i = 1; i < 17; i++) {
        unsigned long long k = s_mrg[i];
        if (k > t1) { t2 = t1; t1 = k; } else if (k > t2) t2 = k;
      }
      int i1 = decodeKey(t1);
      w2 = (i1 == w1) ? decodeKey(t2) : i1;
    }
    if (tid == 0) {
      if (w1 >= base && w1 < base + SLICE) s_avail[w1 - base] = 0;
      if (w2 >= base && w2 < base + SLICE) s_avail[w2 - base] = 0;
      if (seed >= base && seed < base + SLICE) s_assignB[seed - base] |= (unsigned char)(1 << c);
      if (w1 >= base && w1 < base + SLICE) s_assignB[w1 - base] |= (unsigned char)(1 << c);
      if (w2 >= base && w2 < base + SLICE) s_assignB[w2 - base] |= (unsigned char)(1 << c);
    }
    {
      int mc = (seed >= 0) + (w1 >= 0) + (w2 >= 0);
      float invmc = 1.0f / fmaxf((float)mc, 1.0f);
      if (tid < DD) {
        float acc = 0.f;
        if (seed >= 0) acc += x[xb + (size_t)seed * DD + tid];
        if (w1 >= 0) acc += x[xb + (size_t)w1 * DD + tid];
        if (w2 >= 0) acc += x[xb + (size_t)w2 * DD + tid];
        float e = acc * invmc;
        s_hist[c][tid] = e;
        if (blk == 0) out_feat[((size_t)b * MAXC + c) * DD + tid] = e;
      }
    }
    __syncthreads();

    if (c + 1 < MAXC) {
      if (tid < 2 * 3 * HH) {  // gi[c] = bih + Wih @ emb (replicated)
        int row = tid >> 1, half = tid & 1;
        const float4* wr = (const float4*)(Wih + (size_t)row * DD) + half * 16;
        const float4* h4 = (const float4*)s_hist[c] + half * 16;
        float s = 0.f;
#pragma unroll
        for (int i = 0; i < 16; i++) {
          float4 w = wr[i], h = h4[i];
          s += w.x * h.x + w.y * h.y + w.z * h.z + w.w * h.w;
        }
        s += __shfl_xor(s, 1);
        if (half == 0) s_giAll[c][row] = s + s_bih[row];
      }
      __syncthreads();
      for (int t = 0; t <= c; t++) {
        gruStep(t);
        hp ^= 1;
        __syncthreads();
      }
      qFromCtx();
      __syncthreads();
      logitsSel0(c + 1);
      barrier();  // end of phase3
    } else {
      for (int r = tid; r < SLICE * MAXC; r += MT) {
        int i = r / MAXC, cc = r - MAXC * i;
        out_assign[((size_t)(b * NB + base + i)) * MAXC + cc] =
            (float)((s_assignB[i] >> cc) & 1u);
      }
      if (gb == 0) {
        for (int i = tid; i < BB * MAXC * MAXC; i += MT) {
          int j = i % (MAXC * MAXC);
          out_adjm[i] = ((j / MAXC) == (j % MAXC)) ? 0.f : 1.f;
        }
      }
    }
  }
}

extern "C" void kernel_launch(void* const* d_in, const int* in_sizes, int n_in,
                              void* d_out, int out_size, void* d_ws, size_t ws_size,
                              hipStream_t stream) {
  const float* x   = (const float*)d_in[0];
  const float* adj = (const float*)d_in[1];
  const int*   mask= (const int*)d_in[2];
  const float* W1  = (const float*)d_in[3];
  const float* b1  = (const float*)d_in[4];
  const float* W2  = (const float*)d_in[5];
  const float* b2  = (const float*)d_in[6];
  const float* Wc  = (const float*)d_in[7];
  const float* bc  = (const float*)d_in[8];
  const float* Wih = (const float*)d_in[9];
  const float* Whh = (const float*)d_in[10];
  const float* bih = (const float*)d_in[11];
  const float* bhh = (const float*)d_in[12];

  float* ws = (float*)d_ws;
  float* out = (float*)d_out;
  float* out_feat = out;                                     // [B,5,D]
  float* out_adjm = out + (size_t)BB * MAXC * DD;            // [B,5,5]
  float* out_assign = out_adjm + (size_t)BB * MAXC * MAXC;   // [B,N,5]

  hipLaunchKernelGGL(gvp_prep, dim3(385), dim3(1024), 0, stream, x, W1, ws);
  hipLaunchKernelGGL(gvp_main, dim3(BB * BPB), dim3(MT), 0, stream,
                     x, adj, mask, W1, b1, W2, b2, Wc, bc, Wih, Whh, bih, bhh, ws,
                     out_feat, out_adjm, out_assign);
}